// Round 1
// baseline (805.353 us; speedup 1.0000x reference)
//
#include <hip/hip_runtime.h>

// Problem constants (B=8, T=4096, C=512)
#define BB 8
#define TT 4096
#define CC 512
#define MM (BB * TT)   // 32768 rows

typedef short short8 __attribute__((ext_vector_type(8)));
typedef unsigned short ushort8 __attribute__((ext_vector_type(8)));
typedef float f32x4 __attribute__((ext_vector_type(4)));

__device__ __forceinline__ unsigned short f2bf(float f) {
    unsigned int u = __float_as_uint(f);
    u += 0x7FFFu + ((u >> 16) & 1u);   // RNE
    return (unsigned short)(u >> 16);
}
__device__ __forceinline__ float bf2f(unsigned short h) {
    return __uint_as_float(((unsigned int)h) << 16);
}

// async global->LDS, 16B per lane. LDS dest must be wave-uniform base + lane*16.
// generic->AS3 via low-32 truncation (gfx9 LDS aperture is 4GB-aligned).
__device__ __forceinline__ void gl_lds16(const void* g, void* l) {
    __builtin_amdgcn_global_load_lds(
        (__attribute__((address_space(1))) void*)(unsigned long long)g,
        (__attribute__((address_space(3))) void*)(unsigned int)(unsigned long long)l,
        16, 0, 0);
}

__device__ __forceinline__ ushort8 pack8(f32x4 a, f32x4 b) {
    ushort8 r;
    r[0] = f2bf(a.x); r[1] = f2bf(a.y); r[2] = f2bf(a.z); r[3] = f2bf(a.w);
    r[4] = f2bf(b.x); r[5] = f2bf(b.y); r[6] = f2bf(b.z); r[7] = f2bf(b.w);
    return r;
}

// ---------------------------------------------------------------------------
// Kernel 1: transpose + bf16-convert the four 512x512 weights.
// wT[which][n][k] = w[k][n]
// ---------------------------------------------------------------------------
__global__ void transpose_w(const float* __restrict__ wk, const float* __restrict__ wv,
                            const float* __restrict__ wr, const float* __restrict__ wo,
                            unsigned short* __restrict__ wT) {
    const int which = blockIdx.y;
    const float* src = (which == 0) ? wk : (which == 1) ? wv : (which == 2) ? wr : wo;
    const int i = blockIdx.x * 256 + threadIdx.x;     // 0..262143, i = n*512 + k
    const int n = i >> 9;
    const int k = i & 511;
    wT[(size_t)which * (CC * CC) + i] = f2bf(src[(size_t)k * CC + n]);
}

// ---------------------------------------------------------------------------
// Kernel 2: fused time-shift mix + GEMM for k, v, r.
//   which=0: k = (x*mk + xx*(1-mk)) @ wk      -> kbuf (fp32)
//   which=1: v = ...mv... @ wv                -> vbuf (fp32)
//   which=2: sr = sigmoid((...mr...) @ wr)    -> srb (bf16)
// 128x128 tile, BK=32, 4 waves each computing 64x64 via 4x4 mfma 16x16x32 bf16.
// ---------------------------------------------------------------------------
__global__ __launch_bounds__(256, 2) void gemm_kvr(
    const float* __restrict__ x,
    const float* __restrict__ mixk, const float* __restrict__ mixv,
    const float* __restrict__ mixr,
    const unsigned short* __restrict__ wT,   // [3][512][512] (k,v,r) N-major
    float* __restrict__ kbuf, float* __restrict__ vbuf,
    unsigned short* __restrict__ srb) {
    __shared__ unsigned short As[128 * 32];
    __shared__ unsigned short Bs[128 * 32];

    const int tid = threadIdx.x;
    const int pm = blockIdx.x, pn = blockIdx.y, which = blockIdx.z;
    const float* mix = (which == 0) ? mixk : (which == 1) ? mixv : mixr;
    const unsigned short* wTw = wT + (size_t)which * (CC * CC);

    // A staging: thread covers row ar, 16 consecutive k-cols
    const int ar = tid >> 1;              // 0..127
    const int ac = (tid & 1) * 16;        // 0 or 16
    const int gm = pm * 128 + ar;         // global row
    const int t  = gm & (TT - 1);
    const float* xrow  = x + (size_t)gm * CC;
    const float* xprev = xrow - CC;       // only deref'd if t>0
    const bool has_prev = (t != 0);

    // B staging via global_load_lds: 2 x 16B per thread
    const int br = tid >> 2;              // 0..63
    const int bc = (tid & 3) * 8;         // 0,8,16,24 (bf16 cols)
    const unsigned short* bg0 = wTw + (size_t)(pn * 128 + br) * CC + bc;
    const unsigned short* bg1 = bg0 + (size_t)64 * CC;
    unsigned short* bl0 = &Bs[tid * 8];
    unsigned short* bl1 = &Bs[2048 + tid * 8];

    const int wave = tid >> 6, lane = tid & 63;
    const int wr_ = wave >> 1, wc_ = wave & 1;
    const int q = lane >> 4, l16 = lane & 15;

    f32x4 acc[4][4];
#pragma unroll
    for (int i = 0; i < 4; i++)
#pragma unroll
        for (int j = 0; j < 4; j++) acc[i][j] = (f32x4){0.f, 0.f, 0.f, 0.f};

    const f32x4 zero4 = {0.f, 0.f, 0.f, 0.f};
    const f32x4 one4  = {1.f, 1.f, 1.f, 1.f};

    for (int kt = 0; kt < 16; ++kt) {
        const int k0 = kt * 32;
        // async-stage B while we compute the A mix
        gl_lds16(bg0 + k0, bl0);
        gl_lds16(bg1 + k0, bl1);

        const f32x4* xv4 = (const f32x4*)(xrow + k0 + ac);
        const f32x4* xp4 = (const f32x4*)(xprev + k0 + ac);
        const f32x4* mv4 = (const f32x4*)(mix + k0 + ac);
        f32x4 xm[4];
#pragma unroll
        for (int i = 0; i < 4; i++) {
            f32x4 xc = xv4[i];
            f32x4 m  = mv4[i];
            f32x4 xp = has_prev ? xp4[i] : zero4;
            xm[i] = xc * m + xp * (one4 - m);
        }
        *(ushort8*)&As[ar * 32 + ac]     = pack8(xm[0], xm[1]);
        *(ushort8*)&As[ar * 32 + ac + 8] = pack8(xm[2], xm[3]);

        __syncthreads();

        short8 a[4], b[4];
#pragma unroll
        for (int i = 0; i < 4; i++)
            a[i] = *(const short8*)&As[(wr_ * 64 + i * 16 + l16) * 32 + q * 8];
#pragma unroll
        for (int j = 0; j < 4; j++)
            b[j] = *(const short8*)&Bs[(wc_ * 64 + j * 16 + l16) * 32 + q * 8];
#pragma unroll
        for (int i = 0; i < 4; i++)
#pragma unroll
            for (int j = 0; j < 4; j++)
                acc[i][j] = __builtin_amdgcn_mfma_f32_16x16x32_bf16(a[i], b[j], acc[i][j], 0, 0, 0);

        __syncthreads();
    }

    // epilogue: D row = q*4+reg, col = l16 (verified C/D layout)
    const int gm0 = pm * 128 + wr_ * 64;
    const int gn0 = pn * 128 + wc_ * 64;
    if (which == 2) {
#pragma unroll
        for (int i = 0; i < 4; i++)
#pragma unroll
            for (int j = 0; j < 4; j++)
#pragma unroll
                for (int ii = 0; ii < 4; ii++) {
                    const int m = gm0 + i * 16 + q * 4 + ii;
                    const int n = gn0 + j * 16 + l16;
                    const float val = acc[i][j][ii];
                    srb[(size_t)m * CC + n] = f2bf(1.0f / (1.0f + __expf(-val)));
                }
    } else {
        float* ob = (which == 0) ? kbuf : vbuf;
#pragma unroll
        for (int i = 0; i < 4; i++)
#pragma unroll
            for (int j = 0; j < 4; j++)
#pragma unroll
                for (int ii = 0; ii < 4; ii++) {
                    const int m = gm0 + i * 16 + q * 4 + ii;
                    const int n = gn0 + j * 16 + l16;
                    ob[(size_t)m * CC + n] = acc[i][j][ii];
                }
    }
}

// ---------------------------------------------------------------------------
// Kernel 3: WKV recurrence, one thread per (b,c) channel; fuses z = sr*y (bf16).
// ---------------------------------------------------------------------------
__global__ __launch_bounds__(64) void wkv_scan(
    const float* __restrict__ kb, const float* __restrict__ vb,
    const unsigned short* __restrict__ srb,
    const float* __restrict__ sd, const float* __restrict__ sf,
    unsigned short* __restrict__ zb) {
    const int idx = blockIdx.x * 64 + threadIdx.x;  // 0..4095
    const int b = idx >> 9;
    const int c = idx & (CC - 1);
    const size_t base = (size_t)b * TT * CC + c;

    const float w = sd[c] * (1.0f / (float)TT);
    const float u = sf[c] * (1.0f / (float)TT);

    const float* kp = kb + base;
    const float* vp = vb + base;
    const unsigned short* sp = srb + base;
    unsigned short* zp = zb + base;

    float p = 0.f, q = 0.f, o = -1e38f;
#pragma unroll 8
    for (int t = 0; t < TT; ++t) {
        const int off = t * CC;
        const float kt = kp[off];
        const float vt = vp[off];
        const float sr = bf2f(sp[off]);

        const float no = fmaxf(o, u + kt);
        const float A  = __expf(o - no);
        const float Bt = __expf(u + kt - no);
        const float y  = (A * p + Bt * vt) / (A * q + Bt);
        zp[off] = f2bf(sr * y);

        const float no2 = fmaxf(w + o, kt);
        const float A2  = __expf(w + o - no2);
        const float B2  = __expf(kt - no2);
        p = A2 * p + B2 * vt;
        q = A2 * q + B2;
        o = no2;
    }
}

// ---------------------------------------------------------------------------
// Kernel 4: out = z @ wo   (A bf16 via global_load_lds, fp32 epilogue)
// ---------------------------------------------------------------------------
__global__ __launch_bounds__(256, 2) void gemm_out(
    const unsigned short* __restrict__ zb, const unsigned short* __restrict__ woT,
    float* __restrict__ out) {
    __shared__ unsigned short As[128 * 32];
    __shared__ unsigned short Bs[128 * 32];

    const int tid = threadIdx.x;
    const int pm = blockIdx.x, pn = blockIdx.y;

    const int r0 = tid >> 2;              // 0..63
    const int cc = (tid & 3) * 8;
    const unsigned short* ag0 = zb + (size_t)(pm * 128 + r0) * CC + cc;
    const unsigned short* ag1 = ag0 + (size_t)64 * CC;
    const unsigned short* bg0 = woT + (size_t)(pn * 128 + r0) * CC + cc;
    const unsigned short* bg1 = bg0 + (size_t)64 * CC;
    unsigned short* al0 = &As[tid * 8];
    unsigned short* al1 = &As[2048 + tid * 8];
    unsigned short* bl0 = &Bs[tid * 8];
    unsigned short* bl1 = &Bs[2048 + tid * 8];

    const int wave = tid >> 6, lane = tid & 63;
    const int wr_ = wave >> 1, wc_ = wave & 1;
    const int q = lane >> 4, l16 = lane & 15;

    f32x4 acc[4][4];
#pragma unroll
    for (int i = 0; i < 4; i++)
#pragma unroll
        for (int j = 0; j < 4; j++) acc[i][j] = (f32x4){0.f, 0.f, 0.f, 0.f};

    for (int kt = 0; kt < 16; ++kt) {
        const int k0 = kt * 32;
        gl_lds16(ag0 + k0, al0);
        gl_lds16(ag1 + k0, al1);
        gl_lds16(bg0 + k0, bl0);
        gl_lds16(bg1 + k0, bl1);

        __syncthreads();

        short8 a[4], b[4];
#pragma unroll
        for (int i = 0; i < 4; i++)
            a[i] = *(const short8*)&As[(wr_ * 64 + i * 16 + l16) * 32 + q * 8];
#pragma unroll
        for (int j = 0; j < 4; j++)
            b[j] = *(const short8*)&Bs[(wc_ * 64 + j * 16 + l16) * 32 + q * 8];
#pragma unroll
        for (int i = 0; i < 4; i++)
#pragma unroll
            for (int j = 0; j < 4; j++)
                acc[i][j] = __builtin_amdgcn_mfma_f32_16x16x32_bf16(a[i], b[j], acc[i][j], 0, 0, 0);

        __syncthreads();
    }

    const int gm0 = pm * 128 + wr_ * 64;
    const int gn0 = pn * 128 + wc_ * 64;
#pragma unroll
    for (int i = 0; i < 4; i++)
#pragma unroll
        for (int j = 0; j < 4; j++)
#pragma unroll
            for (int ii = 0; ii < 4; ii++) {
                const int m = gm0 + i * 16 + q * 4 + ii;
                const int n = gn0 + j * 16 + l16;
                out[(size_t)m * CC + n] = acc[i][j][ii];
            }
}

// ---------------------------------------------------------------------------
extern "C" void kernel_launch(void* const* d_in, const int* in_sizes, int n_in,
                              void* d_out, int out_size, void* d_ws, size_t ws_size,
                              hipStream_t stream) {
    const float* x  = (const float*)d_in[0];
    const float* sd = (const float*)d_in[1];   // spatial_decay [C]
    const float* sf = (const float*)d_in[2];   // spatial_first [C]
    const float* mk = (const float*)d_in[3];
    const float* mv = (const float*)d_in[4];
    const float* mr = (const float*)d_in[5];
    const float* wk = (const float*)d_in[6];
    const float* wv = (const float*)d_in[7];
    const float* wr = (const float*)d_in[8];
    const float* wo = (const float*)d_in[9];
    float* out = (float*)d_out;

    // ws layout:
    //   [0)           wT bf16 [4][512][512]   (k,v,r,o)   2 MiB
    //   [2MiB)        kbuf fp32 [M][C]        64 MiB
    //   [66MiB)       vbuf fp32 [M][C]        64 MiB
    //   [130MiB)      srb  bf16 [M][C]        32 MiB
    //   [162MiB)      zb   bf16 [M][C]        32 MiB
    char* ws = (char*)d_ws;
    unsigned short* wT = (unsigned short*)ws;
    float* kbuf = (float*)(ws + (size_t)4 * CC * CC * 2);
    float* vbuf = kbuf + (size_t)MM * CC;
    unsigned short* srb = (unsigned short*)(vbuf + (size_t)MM * CC);
    unsigned short* zb  = srb + (size_t)MM * CC;
    unsigned short* woT = wT + (size_t)3 * CC * CC;

    transpose_w<<<dim3((CC * CC) / 256, 4), 256, 0, stream>>>(wk, wv, wr, wo, wT);

    gemm_kvr<<<dim3(MM / 128, CC / 128, 3), 256, 0, stream>>>(
        x, mk, mv, mr, wT, kbuf, vbuf, srb);

    wkv_scan<<<dim3((BB * CC) / 64), 64, 0, stream>>>(kbuf, vbuf, srb, sd, sf, zb);

    gemm_out<<<dim3(MM / 128, CC / 128), 256, 0, stream>>>(zb, woT, out);
}

// Round 3
// 395.632 us; speedup vs baseline: 2.0356x; 2.0356x over previous
//
#include <hip/hip_runtime.h>

// Problem constants (B=8, T=4096, C=512)
#define BB 8
#define TT 4096
#define CC 512
#define MM (BB * TT)   // 32768 rows
#define SS 128         // scan chunks
#define LL 32          // steps per chunk (SS*LL == TT)

typedef short short8 __attribute__((ext_vector_type(8)));
typedef unsigned short ushort8 __attribute__((ext_vector_type(8)));
typedef float f32x4 __attribute__((ext_vector_type(4)));

__device__ __forceinline__ unsigned short f2bf(float f) {
    unsigned int u = __float_as_uint(f);
    u += 0x7FFFu + ((u >> 16) & 1u);   // RNE
    return (unsigned short)(u >> 16);
}
__device__ __forceinline__ float bf2f(unsigned short h) {
    return __uint_as_float(((unsigned int)h) << 16);
}

// async global->LDS, 16B per lane. LDS dest must be wave-uniform base + lane*16.
__device__ __forceinline__ void gl_lds16(const void* g, void* l) {
    __builtin_amdgcn_global_load_lds(
        (__attribute__((address_space(1))) void*)(unsigned long long)g,
        (__attribute__((address_space(3))) void*)(unsigned int)(unsigned long long)l,
        16, 0, 0);
}

__device__ __forceinline__ ushort8 pack8(f32x4 a, f32x4 b) {
    ushort8 r;
    r[0] = f2bf(a.x); r[1] = f2bf(a.y); r[2] = f2bf(a.z); r[3] = f2bf(a.w);
    r[4] = f2bf(b.x); r[5] = f2bf(b.y); r[6] = f2bf(b.z); r[7] = f2bf(b.w);
    return r;
}

// ---------------------------------------------------------------------------
// Kernel 1: transpose + bf16-convert the four 512x512 weights. wT[n][k]=w[k][n]
// ---------------------------------------------------------------------------
__global__ void transpose_w(const float* __restrict__ wk, const float* __restrict__ wv,
                            const float* __restrict__ wr, const float* __restrict__ wo,
                            unsigned short* __restrict__ wT) {
    const int which = blockIdx.y;
    const float* src = (which == 0) ? wk : (which == 1) ? wv : (which == 2) ? wr : wo;
    const int i = blockIdx.x * 256 + threadIdx.x;
    const int n = i >> 9;
    const int k = i & 511;
    wT[(size_t)which * (CC * CC) + i] = f2bf(src[(size_t)k * CC + n]);
}

// ---------------------------------------------------------------------------
// Kernel 2: fused time-shift mix + GEMM for k, v, r. All outputs bf16 now
// (k, v, sigmoid(r)) to keep workspace under the ws_size ceiling.
// ---------------------------------------------------------------------------
__global__ __launch_bounds__(256, 2) void gemm_kvr(
    const float* __restrict__ x,
    const float* __restrict__ mixk, const float* __restrict__ mixv,
    const float* __restrict__ mixr,
    const unsigned short* __restrict__ wT,
    unsigned short* __restrict__ kbuf, unsigned short* __restrict__ vbuf,
    unsigned short* __restrict__ srb) {
    __shared__ unsigned short As[128 * 32];
    __shared__ unsigned short Bs[128 * 32];

    const int tid = threadIdx.x;
    const int pm = blockIdx.x, pn = blockIdx.y, which = blockIdx.z;
    const float* mix = (which == 0) ? mixk : (which == 1) ? mixv : mixr;
    const unsigned short* wTw = wT + (size_t)which * (CC * CC);

    const int ar = tid >> 1;
    const int ac = (tid & 1) * 16;
    const int gm = pm * 128 + ar;
    const int t  = gm & (TT - 1);
    const float* xrow  = x + (size_t)gm * CC;
    const float* xprev = xrow - CC;
    const bool has_prev = (t != 0);

    const int br = tid >> 2;
    const int bc = (tid & 3) * 8;
    const unsigned short* bg0 = wTw + (size_t)(pn * 128 + br) * CC + bc;
    const unsigned short* bg1 = bg0 + (size_t)64 * CC;
    unsigned short* bl0 = &Bs[tid * 8];
    unsigned short* bl1 = &Bs[2048 + tid * 8];

    const int wave = tid >> 6, lane = tid & 63;
    const int wr_ = wave >> 1, wc_ = wave & 1;
    const int q = lane >> 4, l16 = lane & 15;

    f32x4 acc[4][4];
#pragma unroll
    for (int i = 0; i < 4; i++)
#pragma unroll
        for (int j = 0; j < 4; j++) acc[i][j] = (f32x4){0.f, 0.f, 0.f, 0.f};

    const f32x4 zero4 = {0.f, 0.f, 0.f, 0.f};
    const f32x4 one4  = {1.f, 1.f, 1.f, 1.f};

    for (int kt = 0; kt < 16; ++kt) {
        const int k0 = kt * 32;
        gl_lds16(bg0 + k0, bl0);
        gl_lds16(bg1 + k0, bl1);

        const f32x4* xv4 = (const f32x4*)(xrow + k0 + ac);
        const f32x4* xp4 = (const f32x4*)(xprev + k0 + ac);
        const f32x4* mv4 = (const f32x4*)(mix + k0 + ac);
        f32x4 xm[4];
#pragma unroll
        for (int i = 0; i < 4; i++) {
            f32x4 xc = xv4[i];
            f32x4 m  = mv4[i];
            f32x4 xp = has_prev ? xp4[i] : zero4;
            xm[i] = xc * m + xp * (one4 - m);
        }
        *(ushort8*)&As[ar * 32 + ac]     = pack8(xm[0], xm[1]);
        *(ushort8*)&As[ar * 32 + ac + 8] = pack8(xm[2], xm[3]);

        __syncthreads();

        short8 a[4], b[4];
#pragma unroll
        for (int i = 0; i < 4; i++)
            a[i] = *(const short8*)&As[(wr_ * 64 + i * 16 + l16) * 32 + q * 8];
#pragma unroll
        for (int j = 0; j < 4; j++)
            b[j] = *(const short8*)&Bs[(wc_ * 64 + j * 16 + l16) * 32 + q * 8];
#pragma unroll
        for (int i = 0; i < 4; i++)
#pragma unroll
            for (int j = 0; j < 4; j++)
                acc[i][j] = __builtin_amdgcn_mfma_f32_16x16x32_bf16(a[i], b[j], acc[i][j], 0, 0, 0);

        __syncthreads();
    }

    const int gm0 = pm * 128 + wr_ * 64;
    const int gn0 = pn * 128 + wc_ * 64;
    unsigned short* ob = (which == 0) ? kbuf : (which == 1) ? vbuf : srb;
    const bool sig = (which == 2);
#pragma unroll
    for (int i = 0; i < 4; i++)
#pragma unroll
        for (int j = 0; j < 4; j++)
#pragma unroll
            for (int ii = 0; ii < 4; ii++) {
                const int m = gm0 + i * 16 + q * 4 + ii;
                const int n = gn0 + j * 16 + l16;
                float val = acc[i][j][ii];
                if (sig) val = 1.0f / (1.0f + __expf(-val));
                ob[(size_t)m * CC + n] = f2bf(val);
            }
}

// ---------------------------------------------------------------------------
// WKV chunked parallel scan.
// State (p,q,o) represents (P,Q) = (p*e^o, q*e^o); zero state = (0,0,-1e38).
// ---------------------------------------------------------------------------

// Pass 1: per-(s,b,c) chunk-local state from zero init. idx = s*4096 + b*512 + c.
__global__ __launch_bounds__(256) void wkv_part1(
    const unsigned short* __restrict__ kb, const unsigned short* __restrict__ vb,
    const float* __restrict__ sd,
    float* __restrict__ sp_, float* __restrict__ sq_, float* __restrict__ so_) {
    const int idx = blockIdx.x * 256 + threadIdx.x;     // 0 .. S*B*C-1
    const int c = idx & (CC - 1);
    const int b = (idx >> 9) & (BB - 1);
    const int s = idx >> 12;
    const float w = sd[c] * (1.0f / (float)TT);
    const size_t base = ((size_t)b * TT + (size_t)s * LL) * CC + c;
    const unsigned short* kp = kb + base;
    const unsigned short* vp = vb + base;

    float p = 0.f, q = 0.f, o = -1e38f;
#pragma unroll 8
    for (int i = 0; i < LL; ++i) {
        const float kt = bf2f(kp[(size_t)i * CC]);
        const float vt = bf2f(vp[(size_t)i * CC]);
        const float no2 = fmaxf(w + o, kt);
        const float A2  = __expf(w + o - no2);
        const float B2  = __expf(kt - no2);
        p = A2 * p + B2 * vt;
        q = A2 * q + B2;
        o = no2;
    }
    sp_[idx] = p; sq_[idx] = q; so_[idx] = o;
}

// Pass 2: per-(b,c) sequential combine over S chunks -> exclusive prefixes
// (in place). Software-prefetch next chunk's state to overlap load latency.
__global__ __launch_bounds__(256) void wkv_part2(
    const float* __restrict__ sd,
    float* __restrict__ sp_, float* __restrict__ sq_, float* __restrict__ so_) {
    const int idx = blockIdx.x * 256 + threadIdx.x;     // 0..4095 = b*512 + c
    const int c = idx & (CC - 1);
    const float wL = sd[c] * ((float)LL / (float)TT);

    float p = 0.f, q = 0.f, o = -1e38f;                 // exclusive prefix
    float lp = sp_[idx], lq = sq_[idx], lo = so_[idx];  // chunk 0 local
    for (int s = 0; s < SS; ++s) {
        const int off = s * (BB * CC) + idx;
        float nlp = 0.f, nlq = 0.f, nlo = 0.f;
        if (s + 1 < SS) {                                // prefetch next
            nlp = sp_[off + BB * CC];
            nlq = sq_[off + BB * CC];
            nlo = so_[off + BB * CC];
        }
        sp_[off] = p; sq_[off] = q; so_[off] = o;        // write excl. prefix
        const float no = fmaxf(o + wL, lo);
        const float A  = __expf(o + wL - no);
        const float Bc = __expf(lo - no);
        p = A * p + Bc * lp;
        q = A * q + Bc * lq;
        o = no;
        lp = nlp; lq = nlq; lo = nlo;
    }
}

// Pass 3: replay each chunk from its exclusive prefix, emit z = sigmoid(r)*y.
__global__ __launch_bounds__(256) void wkv_part3(
    const unsigned short* __restrict__ kb, const unsigned short* __restrict__ vb,
    const unsigned short* __restrict__ srb,
    const float* __restrict__ sd, const float* __restrict__ sf,
    const float* __restrict__ sp_, const float* __restrict__ sq_,
    const float* __restrict__ so_,
    unsigned short* __restrict__ zb) {
    const int idx = blockIdx.x * 256 + threadIdx.x;
    const int c = idx & (CC - 1);
    const int b = (idx >> 9) & (BB - 1);
    const int s = idx >> 12;
    const float w = sd[c] * (1.0f / (float)TT);
    const float u = sf[c] * (1.0f / (float)TT);
    const size_t base = ((size_t)b * TT + (size_t)s * LL) * CC + c;
    const unsigned short* kp = kb + base;
    const unsigned short* vp = vb + base;
    const unsigned short* sp = srb + base;
    unsigned short* zp = zb + base;

    float p = sp_[idx], q = sq_[idx], o = so_[idx];
#pragma unroll 4
    for (int i = 0; i < LL; ++i) {
        const float kt = bf2f(kp[(size_t)i * CC]);
        const float vt = bf2f(vp[(size_t)i * CC]);
        const float sr = bf2f(sp[(size_t)i * CC]);

        const float no = fmaxf(o, u + kt);
        const float A  = __expf(o - no);
        const float Bt = __expf(u + kt - no);
        const float y  = (A * p + Bt * vt) / (A * q + Bt);
        zp[(size_t)i * CC] = f2bf(sr * y);

        const float no2 = fmaxf(w + o, kt);
        const float A2  = __expf(w + o - no2);
        const float B2  = __expf(kt - no2);
        p = A2 * p + B2 * vt;
        q = A2 * q + B2;
        o = no2;
    }
}

// ---------------------------------------------------------------------------
// Kernel 4: out = z @ wo
// ---------------------------------------------------------------------------
__global__ __launch_bounds__(256, 2) void gemm_out(
    const unsigned short* __restrict__ zb, const unsigned short* __restrict__ woT,
    float* __restrict__ out) {
    __shared__ unsigned short As[128 * 32];
    __shared__ unsigned short Bs[128 * 32];

    const int tid = threadIdx.x;
    const int pm = blockIdx.x, pn = blockIdx.y;

    const int r0 = tid >> 2;
    const int cc = (tid & 3) * 8;
    const unsigned short* ag0 = zb + (size_t)(pm * 128 + r0) * CC + cc;
    const unsigned short* ag1 = ag0 + (size_t)64 * CC;
    const unsigned short* bg0 = woT + (size_t)(pn * 128 + r0) * CC + cc;
    const unsigned short* bg1 = bg0 + (size_t)64 * CC;
    unsigned short* al0 = &As[tid * 8];
    unsigned short* al1 = &As[2048 + tid * 8];
    unsigned short* bl0 = &Bs[tid * 8];
    unsigned short* bl1 = &Bs[2048 + tid * 8];

    const int wave = tid >> 6, lane = tid & 63;
    const int wr_ = wave >> 1, wc_ = wave & 1;
    const int q = lane >> 4, l16 = lane & 15;

    f32x4 acc[4][4];
#pragma unroll
    for (int i = 0; i < 4; i++)
#pragma unroll
        for (int j = 0; j < 4; j++) acc[i][j] = (f32x4){0.f, 0.f, 0.f, 0.f};

    for (int kt = 0; kt < 16; ++kt) {
        const int k0 = kt * 32;
        gl_lds16(ag0 + k0, al0);
        gl_lds16(ag1 + k0, al1);
        gl_lds16(bg0 + k0, bl0);
        gl_lds16(bg1 + k0, bl1);

        __syncthreads();

        short8 a[4], b[4];
#pragma unroll
        for (int i = 0; i < 4; i++)
            a[i] = *(const short8*)&As[(wr_ * 64 + i * 16 + l16) * 32 + q * 8];
#pragma unroll
        for (int j = 0; j < 4; j++)
            b[j] = *(const short8*)&Bs[(wc_ * 64 + j * 16 + l16) * 32 + q * 8];
#pragma unroll
        for (int i = 0; i < 4; i++)
#pragma unroll
            for (int j = 0; j < 4; j++)
                acc[i][j] = __builtin_amdgcn_mfma_f32_16x16x32_bf16(a[i], b[j], acc[i][j], 0, 0, 0);

        __syncthreads();
    }

    const int gm0 = pm * 128 + wr_ * 64;
    const int gn0 = pn * 128 + wc_ * 64;
#pragma unroll
    for (int i = 0; i < 4; i++)
#pragma unroll
        for (int j = 0; j < 4; j++)
#pragma unroll
            for (int ii = 0; ii < 4; ii++) {
                const int m = gm0 + i * 16 + q * 4 + ii;
                const int n = gn0 + j * 16 + l16;
                out[(size_t)m * CC + n] = acc[i][j][ii];
            }
}

// ---------------------------------------------------------------------------
extern "C" void kernel_launch(void* const* d_in, const int* in_sizes, int n_in,
                              void* d_out, int out_size, void* d_ws, size_t ws_size,
                              hipStream_t stream) {
    const float* x  = (const float*)d_in[0];
    const float* sd = (const float*)d_in[1];
    const float* sf = (const float*)d_in[2];
    const float* mk = (const float*)d_in[3];
    const float* mv = (const float*)d_in[4];
    const float* mr = (const float*)d_in[5];
    const float* wk = (const float*)d_in[6];
    const float* wv = (const float*)d_in[7];
    const float* wr = (const float*)d_in[8];
    const float* wo = (const float*)d_in[9];
    float* out = (float*)d_out;

    // ws layout (total 136 MiB; Round-1's 194 MiB passed, 200 MiB crashed):
    //   wT    bf16 [4][512][512]  2 MiB
    //   kbuf  bf16 [M][C]        32 MiB
    //   vbuf  bf16 [M][C]        32 MiB
    //   srb   bf16 [M][C]        32 MiB
    //   zb    bf16 [M][C]        32 MiB
    //   sp/sq/so fp32 [S][B][C]   3 x 2 MiB
    char* ws = (char*)d_ws;
    unsigned short* wT = (unsigned short*)ws;
    unsigned short* kbuf = (unsigned short*)(ws + (size_t)4 * CC * CC * 2);
    unsigned short* vbuf = kbuf + (size_t)MM * CC;
    unsigned short* srb  = vbuf + (size_t)MM * CC;
    unsigned short* zb   = srb + (size_t)MM * CC;
    float* sp_ = (float*)(zb + (size_t)MM * CC);
    float* sq_ = sp_ + (size_t)SS * BB * CC;
    float* so_ = sq_ + (size_t)SS * BB * CC;
    unsigned short* woT = wT + (size_t)3 * CC * CC;

    transpose_w<<<dim3((CC * CC) / 256, 4), 256, 0, stream>>>(wk, wv, wr, wo, wT);

    gemm_kvr<<<dim3(MM / 128, CC / 128, 3), 256, 0, stream>>>(
        x, mk, mv, mr, wT, kbuf, vbuf, srb);

    wkv_part1<<<dim3((SS * BB * CC) / 256), 256, 0, stream>>>(kbuf, vbuf, sd, sp_, sq_, so_);
    wkv_part2<<<dim3((BB * CC) / 256), 256, 0, stream>>>(sd, sp_, sq_, so_);
    wkv_part3<<<dim3((SS * BB * CC) / 256), 256, 0, stream>>>(
        kbuf, vbuf, srb, sd, sf, sp_, sq_, so_, zb);

    gemm_out<<<dim3(MM / 128, CC / 128), 256, 0, stream>>>(zb, woT, out);
}

// Round 4
// 326.626 us; speedup vs baseline: 2.4657x; 1.2113x over previous
//
#include <hip/hip_runtime.h>

// Problem constants (B=8, T=4096, C=512)
#define BB 8
#define TT 4096
#define CC 512
#define MM (BB * TT)   // 32768 rows
#define SS 128         // scan chunks
#define LL 32          // steps per chunk (SS*LL == TT)

typedef short short8 __attribute__((ext_vector_type(8)));
typedef unsigned short ushort8 __attribute__((ext_vector_type(8)));
typedef float f32x4 __attribute__((ext_vector_type(4)));

__device__ __forceinline__ unsigned short f2bf(float f) {
    unsigned int u = __float_as_uint(f);
    u += 0x7FFFu + ((u >> 16) & 1u);   // RNE
    return (unsigned short)(u >> 16);
}
__device__ __forceinline__ float bf2f(unsigned short h) {
    return __uint_as_float(((unsigned int)h) << 16);
}

// async global->LDS, 16B per lane. LDS dest must be wave-uniform base + lane*16.
__device__ __forceinline__ void gl_lds16(const void* g, void* l) {
    __builtin_amdgcn_global_load_lds(
        (__attribute__((address_space(1))) void*)(unsigned long long)g,
        (__attribute__((address_space(3))) void*)(unsigned int)(unsigned long long)l,
        16, 0, 0);
}

__device__ __forceinline__ ushort8 pack8(f32x4 a, f32x4 b) {
    ushort8 r;
    r[0] = f2bf(a.x); r[1] = f2bf(a.y); r[2] = f2bf(a.z); r[3] = f2bf(a.w);
    r[4] = f2bf(b.x); r[5] = f2bf(b.y); r[6] = f2bf(b.z); r[7] = f2bf(b.w);
    return r;
}

// ---------------------------------------------------------------------------
// Kernel 1: transpose + bf16-convert the four 512x512 weights. wT[n][k]=w[k][n]
// ---------------------------------------------------------------------------
__global__ void transpose_w(const float* __restrict__ wk, const float* __restrict__ wv,
                            const float* __restrict__ wr, const float* __restrict__ wo,
                            unsigned short* __restrict__ wT) {
    const int which = blockIdx.y;
    const float* src = (which == 0) ? wk : (which == 1) ? wv : (which == 2) ? wr : wo;
    const int i = blockIdx.x * 256 + threadIdx.x;
    const int n = i >> 9;
    const int k = i & 511;
    wT[(size_t)which * (CC * CC) + i] = f2bf(src[(size_t)k * CC + n]);
}

// ---------------------------------------------------------------------------
// Kernel 2: time-shift mix for all three branches in one memory-bound pass.
// Writes bf16 mixed activations INTO kbuf/vbuf/srb (later transformed
// in-place by gemm_kvr into k / v / sigmoid(r)).
// ---------------------------------------------------------------------------
__global__ __launch_bounds__(256) void mix_kvr(
    const float* __restrict__ x,
    const float* __restrict__ mixk, const float* __restrict__ mixv,
    const float* __restrict__ mixr,
    unsigned short* __restrict__ kx, unsigned short* __restrict__ vx,
    unsigned short* __restrict__ rx) {
    const int idx = blockIdx.x * 256 + threadIdx.x;   // 0 .. MM*CC/8-1
    const int row = idx >> 6;
    const int ch  = (idx & 63) * 8;
    const int t   = row & (TT - 1);
    const size_t off = (size_t)row * CC + ch;
    const float* xr = x + off;

    const f32x4 zero4 = {0.f, 0.f, 0.f, 0.f};
    const f32x4 one4  = {1.f, 1.f, 1.f, 1.f};

    f32x4 xc0 = ((const f32x4*)xr)[0];
    f32x4 xc1 = ((const f32x4*)xr)[1];
    f32x4 xp0 = zero4, xp1 = zero4;
    if (t != 0) {
        xp0 = ((const f32x4*)(xr - CC))[0];
        xp1 = ((const f32x4*)(xr - CC))[1];
    }

    f32x4 m0, m1;
    m0 = ((const f32x4*)(mixk + ch))[0];
    m1 = ((const f32x4*)(mixk + ch))[1];
    *(ushort8*)(kx + off) = pack8(xc0 * m0 + xp0 * (one4 - m0),
                                  xc1 * m1 + xp1 * (one4 - m1));
    m0 = ((const f32x4*)(mixv + ch))[0];
    m1 = ((const f32x4*)(mixv + ch))[1];
    *(ushort8*)(vx + off) = pack8(xc0 * m0 + xp0 * (one4 - m0),
                                  xc1 * m1 + xp1 * (one4 - m1));
    m0 = ((const f32x4*)(mixr + ch))[0];
    m1 = ((const f32x4*)(mixr + ch))[1];
    *(ushort8*)(rx + off) = pack8(xc0 * m0 + xp0 * (one4 - m0),
                                  xc1 * m1 + xp1 * (one4 - m1));
}

// ---------------------------------------------------------------------------
// Kernel 3: in-place GEMM. Block = (64 rows) x (full N=512), which selects
// buffer+weight. Reads its 64 bf16 A-rows fully, then overwrites the same
// rows with the GEMM result (sigmoid applied for which==2). Sole-reader/
// sole-writer per row range => in-place safe.
// A and B staged via global_load_lds w=16. XOR-swizzled LDS col-groups to
// reduce ds_read_b128 bank conflicts (8-way -> 4-way).
// ---------------------------------------------------------------------------
__global__ __launch_bounds__(256, 2) void gemm_kvr(
    const unsigned short* __restrict__ wT,
    unsigned short* __restrict__ kbuf, unsigned short* __restrict__ vbuf,
    unsigned short* __restrict__ srb) {
    __shared__ unsigned short As[64 * 32];    //  4 KiB
    __shared__ unsigned short Bs[512 * 32];   // 32 KiB

    const int tid = threadIdx.x;
    const int pm = blockIdx.x, which = blockIdx.y;
    unsigned short* ab = (which == 0) ? kbuf : (which == 1) ? vbuf : srb;
    const unsigned short* wTw = wT + (size_t)which * (CC * CC);

    // A staging: 256 segs of 16B. seg tid -> row tid>>2, swizzled col-group.
    const int ar  = tid >> 2;
    const int cgs = (tid & 3) ^ ((tid >> 2) & 3);     // swizzled col-group
    const unsigned short* ag = ab + (size_t)(pm * 64 + ar) * CC + cgs * 8;
    unsigned short* al = &As[tid * 8];
    // B staging: 2048 segs, 8 per thread (t*256+tid). Same swizzle since
    // (t*64) % 4 == 0.
    const unsigned short* bgp = wTw + (size_t)ar * CC + cgs * 8;

    const int w = tid >> 6, lane = tid & 63;
    const int q = lane >> 4, l16 = lane & 15;
    const int sw = ((q ^ (l16 & 3))) * 8;             // reader-side swizzle

    f32x4 acc[4][8];
#pragma unroll
    for (int i = 0; i < 4; i++)
#pragma unroll
        for (int j = 0; j < 8; j++) acc[i][j] = (f32x4){0.f, 0.f, 0.f, 0.f};

    for (int kt = 0; kt < 16; ++kt) {
        const int k0 = kt * 32;
        gl_lds16(ag + k0, al);
#pragma unroll
        for (int t = 0; t < 8; ++t)
            gl_lds16(bgp + (size_t)t * 64 * CC + k0, &Bs[(t * 256 + tid) * 8]);

        __syncthreads();

        short8 a[4], b[8];
#pragma unroll
        for (int i = 0; i < 4; i++)
            a[i] = *(const short8*)&As[(i * 16 + l16) * 32 + sw];
#pragma unroll
        for (int j = 0; j < 8; j++)
            b[j] = *(const short8*)&Bs[(w * 128 + j * 16 + l16) * 32 + sw];
#pragma unroll
        for (int i = 0; i < 4; i++)
#pragma unroll
            for (int j = 0; j < 8; j++)
                acc[i][j] = __builtin_amdgcn_mfma_f32_16x16x32_bf16(a[i], b[j], acc[i][j], 0, 0, 0);

        __syncthreads();
    }

    // epilogue: row = i*16 + q*4 + ii, col = w*128 + j*16 + l16 (in-place)
    const bool sig = (which == 2);
    const size_t rb = (size_t)pm * 64;
#pragma unroll
    for (int i = 0; i < 4; i++)
#pragma unroll
        for (int j = 0; j < 8; j++)
#pragma unroll
            for (int ii = 0; ii < 4; ii++) {
                const int m = i * 16 + q * 4 + ii;
                const int n = w * 128 + j * 16 + l16;
                float val = acc[i][j][ii];
                if (sig) val = 1.0f / (1.0f + __expf(-val));
                ab[(rb + m) * CC + n] = f2bf(val);
            }
}

// ---------------------------------------------------------------------------
// WKV chunked parallel scan (unchanged from Round 3).
// ---------------------------------------------------------------------------
__global__ __launch_bounds__(256) void wkv_part1(
    const unsigned short* __restrict__ kb, const unsigned short* __restrict__ vb,
    const float* __restrict__ sd,
    float* __restrict__ sp_, float* __restrict__ sq_, float* __restrict__ so_) {
    const int idx = blockIdx.x * 256 + threadIdx.x;
    const int c = idx & (CC - 1);
    const int b = (idx >> 9) & (BB - 1);
    const int s = idx >> 12;
    const float w = sd[c] * (1.0f / (float)TT);
    const size_t base = ((size_t)b * TT + (size_t)s * LL) * CC + c;
    const unsigned short* kp = kb + base;
    const unsigned short* vp = vb + base;

    float p = 0.f, q = 0.f, o = -1e38f;
#pragma unroll 8
    for (int i = 0; i < LL; ++i) {
        const float kt = bf2f(kp[(size_t)i * CC]);
        const float vt = bf2f(vp[(size_t)i * CC]);
        const float no2 = fmaxf(w + o, kt);
        const float A2  = __expf(w + o - no2);
        const float B2  = __expf(kt - no2);
        p = A2 * p + B2 * vt;
        q = A2 * q + B2;
        o = no2;
    }
    sp_[idx] = p; sq_[idx] = q; so_[idx] = o;
}

__global__ __launch_bounds__(256) void wkv_part2(
    const float* __restrict__ sd,
    float* __restrict__ sp_, float* __restrict__ sq_, float* __restrict__ so_) {
    const int idx = blockIdx.x * 256 + threadIdx.x;
    const int c = idx & (CC - 1);
    const float wL = sd[c] * ((float)LL / (float)TT);

    float p = 0.f, q = 0.f, o = -1e38f;
    float lp = sp_[idx], lq = sq_[idx], lo = so_[idx];
    for (int s = 0; s < SS; ++s) {
        const int off = s * (BB * CC) + idx;
        float nlp = 0.f, nlq = 0.f, nlo = 0.f;
        if (s + 1 < SS) {
            nlp = sp_[off + BB * CC];
            nlq = sq_[off + BB * CC];
            nlo = so_[off + BB * CC];
        }
        sp_[off] = p; sq_[off] = q; so_[off] = o;
        const float no = fmaxf(o + wL, lo);
        const float A  = __expf(o + wL - no);
        const float Bc = __expf(lo - no);
        p = A * p + Bc * lp;
        q = A * q + Bc * lq;
        o = no;
        lp = nlp; lq = nlq; lo = nlo;
    }
}

__global__ __launch_bounds__(256) void wkv_part3(
    const unsigned short* __restrict__ kb, const unsigned short* __restrict__ vb,
    const unsigned short* __restrict__ srb,
    const float* __restrict__ sd, const float* __restrict__ sf,
    const float* __restrict__ sp_, const float* __restrict__ sq_,
    const float* __restrict__ so_,
    unsigned short* __restrict__ zb) {
    const int idx = blockIdx.x * 256 + threadIdx.x;
    const int c = idx & (CC - 1);
    const int b = (idx >> 9) & (BB - 1);
    const int s = idx >> 12;
    const float w = sd[c] * (1.0f / (float)TT);
    const float u = sf[c] * (1.0f / (float)TT);
    const size_t base = ((size_t)b * TT + (size_t)s * LL) * CC + c;
    const unsigned short* kp = kb + base;
    const unsigned short* vp = vb + base;
    const unsigned short* sp = srb + base;
    unsigned short* zp = zb + base;

    float p = sp_[idx], q = sq_[idx], o = so_[idx];
#pragma unroll 4
    for (int i = 0; i < LL; ++i) {
        const float kt = bf2f(kp[(size_t)i * CC]);
        const float vt = bf2f(vp[(size_t)i * CC]);
        const float sr = bf2f(sp[(size_t)i * CC]);

        const float no = fmaxf(o, u + kt);
        const float A  = __expf(o - no);
        const float Bt = __expf(u + kt - no);
        const float y  = (A * p + Bt * vt) / (A * q + Bt);
        zp[(size_t)i * CC] = f2bf(sr * y);

        const float no2 = fmaxf(w + o, kt);
        const float A2  = __expf(w + o - no2);
        const float B2  = __expf(kt - no2);
        p = A2 * p + B2 * vt;
        q = A2 * q + B2;
        o = no2;
    }
}

// ---------------------------------------------------------------------------
// Kernel 4: out = z @ wo (unchanged)
// ---------------------------------------------------------------------------
__global__ __launch_bounds__(256, 2) void gemm_out(
    const unsigned short* __restrict__ zb, const unsigned short* __restrict__ woT,
    float* __restrict__ out) {
    __shared__ unsigned short As[128 * 32];
    __shared__ unsigned short Bs[128 * 32];

    const int tid = threadIdx.x;
    const int pm = blockIdx.x, pn = blockIdx.y;

    const int r0 = tid >> 2;
    const int cc = (tid & 3) * 8;
    const unsigned short* ag0 = zb + (size_t)(pm * 128 + r0) * CC + cc;
    const unsigned short* ag1 = ag0 + (size_t)64 * CC;
    const unsigned short* bg0 = woT + (size_t)(pn * 128 + r0) * CC + cc;
    const unsigned short* bg1 = bg0 + (size_t)64 * CC;
    unsigned short* al0 = &As[tid * 8];
    unsigned short* al1 = &As[2048 + tid * 8];
    unsigned short* bl0 = &Bs[tid * 8];
    unsigned short* bl1 = &Bs[2048 + tid * 8];

    const int wave = tid >> 6, lane = tid & 63;
    const int wr_ = wave >> 1, wc_ = wave & 1;
    const int q = lane >> 4, l16 = lane & 15;

    f32x4 acc[4][4];
#pragma unroll
    for (int i = 0; i < 4; i++)
#pragma unroll
        for (int j = 0; j < 4; j++) acc[i][j] = (f32x4){0.f, 0.f, 0.f, 0.f};

    for (int kt = 0; kt < 16; ++kt) {
        const int k0 = kt * 32;
        gl_lds16(ag0 + k0, al0);
        gl_lds16(ag1 + k0, al1);
        gl_lds16(bg0 + k0, bl0);
        gl_lds16(bg1 + k0, bl1);

        __syncthreads();

        short8 a[4], b[4];
#pragma unroll
        for (int i = 0; i < 4; i++)
            a[i] = *(const short8*)&As[(wr_ * 64 + i * 16 + l16) * 32 + q * 8];
#pragma unroll
        for (int j = 0; j < 4; j++)
            b[j] = *(const short8*)&Bs[(wc_ * 64 + j * 16 + l16) * 32 + q * 8];
#pragma unroll
        for (int i = 0; i < 4; i++)
#pragma unroll
            for (int j = 0; j < 4; j++)
                acc[i][j] = __builtin_amdgcn_mfma_f32_16x16x32_bf16(a[i], b[j], acc[i][j], 0, 0, 0);

        __syncthreads();
    }

    const int gm0 = pm * 128 + wr_ * 64;
    const int gn0 = pn * 128 + wc_ * 64;
#pragma unroll
    for (int i = 0; i < 4; i++)
#pragma unroll
        for (int j = 0; j < 4; j++)
#pragma unroll
            for (int ii = 0; ii < 4; ii++) {
                const int m = gm0 + i * 16 + q * 4 + ii;
                const int n = gn0 + j * 16 + l16;
                out[(size_t)m * CC + n] = acc[i][j][ii];
            }
}

// ---------------------------------------------------------------------------
extern "C" void kernel_launch(void* const* d_in, const int* in_sizes, int n_in,
                              void* d_out, int out_size, void* d_ws, size_t ws_size,
                              hipStream_t stream) {
    const float* x  = (const float*)d_in[0];
    const float* sd = (const float*)d_in[1];
    const float* sf = (const float*)d_in[2];
    const float* mk = (const float*)d_in[3];
    const float* mv = (const float*)d_in[4];
    const float* mr = (const float*)d_in[5];
    const float* wk = (const float*)d_in[6];
    const float* wv = (const float*)d_in[7];
    const float* wr = (const float*)d_in[8];
    const float* wo = (const float*)d_in[9];
    float* out = (float*)d_out;

    // ws layout (136 MiB total; ws ceiling is in [194,200) MiB):
    //   wT    bf16 [4][512][512]  2 MiB
    //   kbuf  bf16 [M][C]        32 MiB   (mixed xk, then k in-place)
    //   vbuf  bf16 [M][C]        32 MiB   (mixed xv, then v in-place)
    //   srb   bf16 [M][C]        32 MiB   (mixed xr, then sigmoid(r) in-place)
    //   zb    bf16 [M][C]        32 MiB
    //   sp/sq/so fp32 [S][B][C]   3 x 2 MiB
    char* ws = (char*)d_ws;
    unsigned short* wT = (unsigned short*)ws;
    unsigned short* kbuf = (unsigned short*)(ws + (size_t)4 * CC * CC * 2);
    unsigned short* vbuf = kbuf + (size_t)MM * CC;
    unsigned short* srb  = vbuf + (size_t)MM * CC;
    unsigned short* zb   = srb + (size_t)MM * CC;
    float* sp_ = (float*)(zb + (size_t)MM * CC);
    float* sq_ = sp_ + (size_t)SS * BB * CC;
    float* so_ = sq_ + (size_t)SS * BB * CC;
    unsigned short* woT = wT + (size_t)3 * CC * CC;

    transpose_w<<<dim3((CC * CC) / 256, 4), 256, 0, stream>>>(wk, wv, wr, wo, wT);

    mix_kvr<<<dim3((MM * CC / 8) / 256), 256, 0, stream>>>(
        x, mk, mv, mr, kbuf, vbuf, srb);

    gemm_kvr<<<dim3(MM / 64, 3), 256, 0, stream>>>(wT, kbuf, vbuf, srb);

    wkv_part1<<<dim3((SS * BB * CC) / 256), 256, 0, stream>>>(kbuf, vbuf, sd, sp_, sq_, so_);
    wkv_part2<<<dim3((BB * CC) / 256), 256, 0, stream>>>(sd, sp_, sq_, so_);
    wkv_part3<<<dim3((SS * BB * CC) / 256), 256, 0, stream>>>(
        kbuf, vbuf, srb, sd, sf, sp_, sq_, so_, zb);

    gemm_out<<<dim3(MM / 128, CC / 128), 256, 0, stream>>>(zb, woT, out);
}